// Round 1
// baseline (666.650 us; speedup 1.0000x reference)
//
#include <hip/hip_runtime.h>

#define EPS 1e-3f

// Problem constants
// x: [16,56,56,128], out: [16,28,28,256], G=32 groups, BF=4
#define NPIX   50176   // 16*56*56
#define NOPIX  12544   // 16*28*28

// ws float offsets
#define OFF_ST1  0        // [32][128][2] interleaved (s,t) for bn1
#define OFF_S2   8192     // [32][4]
#define OFF_T2   8320
#define OFF_S3   8448
#define OFF_T3   8576
#define OFF_BSUM 8704     // [256]
#define OFF_U    8960     // [16*56*56*128] fp32 intermediate

__global__ __launch_bounds__(256)
void prep_kernel(const float* __restrict__ g1, const float* __restrict__ be1,
                 const float* __restrict__ m1, const float* __restrict__ v1,
                 const float* __restrict__ b1, const float* __restrict__ g2,
                 const float* __restrict__ be2, const float* __restrict__ m2,
                 const float* __restrict__ v2, const float* __restrict__ b3,
                 const float* __restrict__ g3, const float* __restrict__ be3,
                 const float* __restrict__ m3, const float* __restrict__ v3,
                 const float* __restrict__ b2, float* __restrict__ ws) {
    int tid = threadIdx.x;
    for (int i = tid; i < 4096; i += 256) {
        float s = g1[i] * rsqrtf(v1[i] + EPS);
        float t = be1[i] - m1[i] * s;
        ws[OFF_ST1 + 2*i]     = s;
        ws[OFF_ST1 + 2*i + 1] = t;
    }
    if (tid < 128) {
        float s2 = g2[tid] * rsqrtf(v2[tid] + EPS);
        ws[OFF_S2 + tid] = s2;
        ws[OFF_T2 + tid] = be2[tid] + (b1[tid] - m2[tid]) * s2;
        float s3 = g3[tid] * rsqrtf(v3[tid] + EPS);
        ws[OFF_S3 + tid] = s3;
        ws[OFF_T3 + tid] = be3[tid] + (b3[tid] - m3[tid]) * s3;
    }
    float acc = 0.f;
    for (int g = 0; g < 32; ++g) acc += b2[g*256 + tid];
    ws[OFF_BSUM + tid] = acc;
}

// Stage 1: U[pix, g*4+f] = relu(s2*(sum_c relu(x*s1+t1)*W1) + t2)
// block = 256 threads = 8 pixels x 32 groups
__global__ __launch_bounds__(256)
void stage1_kernel(const float* __restrict__ x,
                   const float* __restrict__ W1,   // [32,128,4]
                   float* __restrict__ ws) {
    __shared__ float xs[8 * 128];
    int tid = threadIdx.x;
    // stage 8 pixels of x (contiguous 1024 floats) into LDS
    ((float4*)xs)[tid] = ((const float4*)x)[(size_t)blockIdx.x * 256 + tid];
    __syncthreads();

    int p = tid >> 5;   // pixel 0..7
    int g = tid & 31;   // group 0..31
    const float2* st = (const float2*)(ws + OFF_ST1) + g * 128;
    const float4* w1 = (const float4*)W1 + g * 128;
    const float*  xp = xs + p * 128;

    float a0 = 0.f, a1 = 0.f, a2 = 0.f, a3 = 0.f;
    #pragma unroll 4
    for (int c = 0; c < 128; ++c) {
        float2 s = st[c];
        float z = fmaxf(fmaf(xp[c], s.x, s.y), 0.f);
        float4 w = w1[c];
        a0 = fmaf(z, w.x, a0);
        a1 = fmaf(z, w.y, a1);
        a2 = fmaf(z, w.z, a2);
        a3 = fmaf(z, w.w, a3);
    }
    float4 s2v = *((const float4*)(ws + OFF_S2) + g);
    float4 t2v = *((const float4*)(ws + OFF_T2) + g);
    float4 u;
    u.x = fmaxf(fmaf(a0, s2v.x, t2v.x), 0.f);
    u.y = fmaxf(fmaf(a1, s2v.y, t2v.y), 0.f);
    u.z = fmaxf(fmaf(a2, s2v.z, t2v.z), 0.f);
    u.w = fmaxf(fmaf(a3, s2v.w, t2v.w), 0.f);
    // U float4 index = pix*32 + g = blockIdx*256 + tid
    ((float4*)(ws + OFF_U))[(size_t)blockIdx.x * 256 + tid] = u;
}

// Stage 2: 3x3 s2 conv + bn3/relu -> v[128]; out = v @ W2cat + bsum + res
// block = 256 threads handles 8 output pixels
__global__ __launch_bounds__(256)
void stage2_kernel(const float* __restrict__ x,
                   const float* __restrict__ W3,   // [32,3,3,4,4]
                   const float* __restrict__ W2,   // [32,4,256] = [128,256]
                   const float* __restrict__ ws,
                   float* __restrict__ out) {
    __shared__ float vs[8 * 128];
    __shared__ float res_s[8];
    int tid = threadIdx.x;
    int opBase = blockIdx.x * 8;
    const float4* U4 = (const float4*)(ws + OFF_U);

    // ---- v computation: thread covers k = tid&127 for 4 pixels ----
    {
        int k = tid & 127;
        int half = tid >> 7;
        int g = k >> 2;
        int f = k & 3;
        float w3r[36];
        #pragma unroll
        for (int kk = 0; kk < 9; ++kk)
            #pragma unroll
            for (int ci = 0; ci < 4; ++ci)
                w3r[kk*4 + ci] = W3[g*144 + kk*16 + ci*4 + f];
        float s3k = ws[OFF_S3 + k];
        float t3k = ws[OFF_T3 + k];
        #pragma unroll
        for (int j = 0; j < 4; ++j) {
            int p = half * 4 + j;
            int op = opBase + p;
            int b = op / 784;
            int r = op - b * 784;
            int oh = r / 28;
            int ow = r - oh * 28;
            float acc = 0.f;
            #pragma unroll
            for (int kh = 0; kh < 3; ++kh) {
                int ih = 2*oh - 1 + kh;
                if (ih < 0) continue;        // ih <= 55 always
                #pragma unroll
                for (int kw = 0; kw < 3; ++kw) {
                    int iw = 2*ow - 1 + kw;
                    if (iw < 0) continue;    // iw <= 55 always
                    float4 u = U4[((size_t)(b*56 + ih)*56 + iw)*32 + g];
                    int kk = kh*3 + kw;
                    acc = fmaf(u.x, w3r[kk*4+0], acc);
                    acc = fmaf(u.y, w3r[kk*4+1], acc);
                    acc = fmaf(u.z, w3r[kk*4+2], acc);
                    acc = fmaf(u.w, w3r[kk*4+3], acc);
                }
            }
            vs[p*128 + k] = fmaxf(fmaf(acc, s3k, t3k), 0.f);
        }
    }
    // ---- residual: res[p] = sum_c x[b, 2oh, 2ow, c] ----
    {
        int p = tid >> 5;
        int l = tid & 31;
        int op = opBase + p;
        int b = op / 784;
        int r = op - b * 784;
        int oh = r / 28;
        int ow = r - oh * 28;
        const float* xp = x + ((size_t)(b*56 + 2*oh)*56 + 2*ow) * 128;
        float v = xp[l] + xp[l+32] + xp[l+64] + xp[l+96];
        for (int off = 16; off; off >>= 1) v += __shfl_down(v, off, 32);
        if (l == 0) res_s[p] = v;
    }
    __syncthreads();

    // ---- final GEMM: out[op, co] = sum_k vs[p][k]*W2[k][co] + bsum + res ----
    int co = tid;
    float bs = ws[OFF_BSUM + co];
    float acc[8];
    #pragma unroll
    for (int p = 0; p < 8; ++p) acc[p] = bs;
    #pragma unroll 4
    for (int k = 0; k < 128; ++k) {
        float wv = W2[k*256 + co];
        #pragma unroll
        for (int p = 0; p < 8; ++p)
            acc[p] = fmaf(vs[p*128 + k], wv, acc[p]);
    }
    #pragma unroll
    for (int p = 0; p < 8; ++p)
        out[(size_t)(opBase + p) * 256 + co] = acc[p] + res_s[p];
}

extern "C" void kernel_launch(void* const* d_in, const int* in_sizes, int n_in,
                              void* d_out, int out_size, void* d_ws, size_t ws_size,
                              hipStream_t stream) {
    const float* x   = (const float*)d_in[0];
    const float* g1  = (const float*)d_in[1];
    const float* be1 = (const float*)d_in[2];
    const float* m1  = (const float*)d_in[3];
    const float* v1  = (const float*)d_in[4];
    const float* W1  = (const float*)d_in[5];
    const float* b1  = (const float*)d_in[6];
    const float* g2  = (const float*)d_in[7];
    const float* be2 = (const float*)d_in[8];
    const float* m2  = (const float*)d_in[9];
    const float* v2  = (const float*)d_in[10];
    const float* W3  = (const float*)d_in[11];
    const float* b3  = (const float*)d_in[12];
    const float* g3  = (const float*)d_in[13];
    const float* be3 = (const float*)d_in[14];
    const float* m3  = (const float*)d_in[15];
    const float* v3  = (const float*)d_in[16];
    const float* W2  = (const float*)d_in[17];
    const float* b2  = (const float*)d_in[18];
    float* out = (float*)d_out;
    float* ws  = (float*)d_ws;

    prep_kernel<<<1, 256, 0, stream>>>(g1, be1, m1, v1, b1, g2, be2, m2, v2,
                                       b3, g3, be3, m3, v3, b2, ws);
    stage1_kernel<<<NPIX / 8, 256, 0, stream>>>(x, W1, ws);
    stage2_kernel<<<NOPIX / 8, 256, 0, stream>>>(x, W3, W2, ws, out);
}

// Round 2
// 207.655 us; speedup vs baseline: 3.2104x; 3.2104x over previous
//
#include <hip/hip_runtime.h>

#define EPS 1e-3f

// x: [16,56,56,128], out: [16,28,28,256], G=32 groups, BF=4
#define NPIX   50176   // 16*56*56
#define NOPIX  12544   // 16*28*28

// ws float offsets
#define OFF_ST1  0        // [32][128][2] interleaved (s,t) for bn1
#define OFF_S2   8192     // [32][4]
#define OFF_T2   8320
#define OFF_T3   8576
#define OFF_BSUM 8704     // [256]
#define OFF_W3S  8960     // [32][144] W3 pre-scaled by s3
#define OFF_U    13568    // [16*56*56*128] fp32 intermediate

__global__ __launch_bounds__(256)
void prep_kernel(const float* __restrict__ g1, const float* __restrict__ be1,
                 const float* __restrict__ m1, const float* __restrict__ v1,
                 const float* __restrict__ b1, const float* __restrict__ g2,
                 const float* __restrict__ be2, const float* __restrict__ m2,
                 const float* __restrict__ v2, const float* __restrict__ W3,
                 const float* __restrict__ b3, const float* __restrict__ g3,
                 const float* __restrict__ be3, const float* __restrict__ m3,
                 const float* __restrict__ v3, const float* __restrict__ b2,
                 float* __restrict__ ws) {
    int tid = threadIdx.x;
    for (int i = tid; i < 4096; i += 256) {
        float s = g1[i] * rsqrtf(v1[i] + EPS);
        float t = be1[i] - m1[i] * s;
        ws[OFF_ST1 + 2*i]     = s;
        ws[OFF_ST1 + 2*i + 1] = t;
    }
    if (tid < 128) {
        float s2 = g2[tid] * rsqrtf(v2[tid] + EPS);
        ws[OFF_S2 + tid] = s2;
        ws[OFF_T2 + tid] = be2[tid] + (b1[tid] - m2[tid]) * s2;
        float s3 = g3[tid] * rsqrtf(v3[tid] + EPS);
        ws[OFF_T3 + tid] = be3[tid] + (b3[tid] - m3[tid]) * s3;
    }
    // W3 pre-scaled by s3 (per output channel f of its group)
    for (int i = tid; i < 4608; i += 256) {
        int g = i / 144;
        int f = i & 3;
        int k = g*4 + f;
        float s3 = g3[k] * rsqrtf(v3[k] + EPS);
        ws[OFF_W3S + i] = W3[i] * s3;
    }
    if (tid < 256) {
        float acc = 0.f;
        for (int g = 0; g < 32; ++g) acc += b2[g*256 + tid];
        ws[OFF_BSUM + tid] = acc;
    }
}

// Stage 1: U[pix, g*4+f] = relu(s2*(sum_c relu(x*s1+t1)*W1) + t2)
// block = 256 threads = 4 waves; wave = 64 pixels, each wave does 8 groups.
// Tables read with wave-uniform indices -> scalar loads (broadcast).
__global__ __launch_bounds__(256)
void stage1_kernel(const float* __restrict__ x,
                   const float* __restrict__ W1,     // [32,128,4]
                   const float* __restrict__ tabs,   // ws
                   float* __restrict__ uout) {       // ws + OFF_U
    __shared__ float xs[64 * 129];
    int tid = threadIdx.x;
    // stage 64 pixels (8192 floats) of x into LDS, padded stride 129
    const float4* x4 = (const float4*)x + (size_t)blockIdx.x * 2048;
    for (int i = tid; i < 2048; i += 256) {
        float4 v = x4[i];
        int p = i >> 5, c4 = (i & 31) << 2;
        float* d = xs + p * 129 + c4;
        d[0] = v.x; d[1] = v.y; d[2] = v.z; d[3] = v.w;
    }
    __syncthreads();

    int lane = tid & 63;
    int gbase = __builtin_amdgcn_readfirstlane(tid >> 6) * 8;
    const float* xp = xs + lane * 129;
    size_t pxIdx = (size_t)blockIdx.x * 64 + lane;
    float4* U4 = (float4*)uout;

    for (int gi = 0; gi < 8; ++gi) {
        int g = gbase + gi;
        const float2* st = (const float2*)(tabs + OFF_ST1) + g * 128;
        const float4* w1 = (const float4*)W1 + g * 128;
        float a0 = 0.f, a1 = 0.f, a2 = 0.f, a3 = 0.f;
        #pragma unroll 8
        for (int c = 0; c < 128; ++c) {
            float2 s = st[c];          // uniform -> s_load
            float4 w = w1[c];          // uniform -> s_load
            float z = fmaxf(fmaf(xp[c], s.x, s.y), 0.f);
            a0 = fmaf(z, w.x, a0);
            a1 = fmaf(z, w.y, a1);
            a2 = fmaf(z, w.z, a2);
            a3 = fmaf(z, w.w, a3);
        }
        float4 s2v = ((const float4*)(tabs + OFF_S2))[g];
        float4 t2v = ((const float4*)(tabs + OFF_T2))[g];
        float4 u;
        u.x = fmaxf(fmaf(a0, s2v.x, t2v.x), 0.f);
        u.y = fmaxf(fmaf(a1, s2v.y, t2v.y), 0.f);
        u.z = fmaxf(fmaf(a2, s2v.z, t2v.z), 0.f);
        u.w = fmaxf(fmaf(a3, s2v.w, t2v.w), 0.f);
        U4[pxIdx * 32 + g] = u;
    }
}

// Stage 2: 3x3 s2 conv (+bn3/relu) -> vs[8][128]; out = vs @ W2 + bsum + res
// block = 256 threads, 8 output pixels.
__global__ __launch_bounds__(256)
void stage2_kernel(const float* __restrict__ x,
                   const float* __restrict__ W2,     // [128,256]
                   const float* __restrict__ tabs,   // ws
                   const float* __restrict__ U,      // ws + OFF_U
                   float* __restrict__ out) {
    __shared__ float w3s[32 * 145];  // stride 145 -> conflict-free across g
    __shared__ float vs[8 * 128];
    __shared__ float res_s[8];
    int tid = threadIdx.x;
    for (int i = tid; i < 4608; i += 256) {
        int g = i / 144, idx = i - g * 144;
        w3s[g * 145 + idx] = tabs[OFF_W3S + i];
    }
    __syncthreads();

    int opBase = blockIdx.x * 8;
    int p = tid >> 5, g = tid & 31;
    int op = opBase + p;
    int b = op / 784;
    int r = op - b * 784;
    int oh = r / 28;
    int ow = r - oh * 28;

    // ---- phase A: 3x3 stride-2 conv for this (pixel, group) ----
    {
        const float4* U4 = (const float4*)U;
        const float* wg = w3s + g * 145;
        float a0 = 0.f, a1 = 0.f, a2 = 0.f, a3 = 0.f;
        #pragma unroll
        for (int kh = 0; kh < 3; ++kh) {
            int ih = 2*oh - 1 + kh;
            if (ih < 0) continue;
            #pragma unroll
            for (int kw = 0; kw < 3; ++kw) {
                int iw = 2*ow - 1 + kw;
                if (iw < 0) continue;
                float4 u = U4[((size_t)(b*56 + ih)*56 + iw)*32 + g];
                const float* wk = wg + (kh*3 + kw) * 16;
                a0 = fmaf(u.x, wk[0],  a0); a1 = fmaf(u.x, wk[1],  a1);
                a2 = fmaf(u.x, wk[2],  a2); a3 = fmaf(u.x, wk[3],  a3);
                a0 = fmaf(u.y, wk[4],  a0); a1 = fmaf(u.y, wk[5],  a1);
                a2 = fmaf(u.y, wk[6],  a2); a3 = fmaf(u.y, wk[7],  a3);
                a0 = fmaf(u.z, wk[8],  a0); a1 = fmaf(u.z, wk[9],  a1);
                a2 = fmaf(u.z, wk[10], a2); a3 = fmaf(u.z, wk[11], a3);
                a0 = fmaf(u.w, wk[12], a0); a1 = fmaf(u.w, wk[13], a1);
                a2 = fmaf(u.w, wk[14], a2); a3 = fmaf(u.w, wk[15], a3);
            }
        }
        float4 t3v = ((const float4*)(tabs + OFF_T3))[g];
        float4 v;
        v.x = fmaxf(a0 + t3v.x, 0.f);
        v.y = fmaxf(a1 + t3v.y, 0.f);
        v.z = fmaxf(a2 + t3v.z, 0.f);
        v.w = fmaxf(a3 + t3v.w, 0.f);
        ((float4*)vs)[p * 32 + g] = v;
    }
    // ---- residual: res[p] = sum_c x[b, 2oh, 2ow, c] ----
    {
        const float* xp = x + ((size_t)(b*56 + 2*oh)*56 + 2*ow) * 128;
        float v = xp[g] + xp[g+32] + xp[g+64] + xp[g+96];
        for (int off = 16; off; off >>= 1) v += __shfl_down(v, off, 32);
        if (g == 0) res_s[p] = v;
    }
    __syncthreads();

    // ---- phase B: out[op, co] = sum_k vs[p][k]*W2[k][co] + bsum + res ----
    int co = tid;
    float bs = tabs[OFF_BSUM + co];
    float acc[8];
    #pragma unroll
    for (int q = 0; q < 8; ++q) acc[q] = bs;
    const float4* vs4 = (const float4*)vs;
    #pragma unroll 4
    for (int k4 = 0; k4 < 32; ++k4) {
        float w0 = W2[(4*k4+0)*256 + co];
        float w1 = W2[(4*k4+1)*256 + co];
        float w2 = W2[(4*k4+2)*256 + co];
        float w3 = W2[(4*k4+3)*256 + co];
        #pragma unroll
        for (int q = 0; q < 8; ++q) {
            float4 v = vs4[q*32 + k4];
            acc[q] = fmaf(v.x, w0, acc[q]);
            acc[q] = fmaf(v.y, w1, acc[q]);
            acc[q] = fmaf(v.z, w2, acc[q]);
            acc[q] = fmaf(v.w, w3, acc[q]);
        }
    }
    #pragma unroll
    for (int q = 0; q < 8; ++q)
        out[(size_t)(opBase + q) * 256 + co] = acc[q] + res_s[q];
}

extern "C" void kernel_launch(void* const* d_in, const int* in_sizes, int n_in,
                              void* d_out, int out_size, void* d_ws, size_t ws_size,
                              hipStream_t stream) {
    const float* x   = (const float*)d_in[0];
    const float* g1  = (const float*)d_in[1];
    const float* be1 = (const float*)d_in[2];
    const float* m1  = (const float*)d_in[3];
    const float* v1  = (const float*)d_in[4];
    const float* W1  = (const float*)d_in[5];
    const float* b1  = (const float*)d_in[6];
    const float* g2  = (const float*)d_in[7];
    const float* be2 = (const float*)d_in[8];
    const float* m2  = (const float*)d_in[9];
    const float* v2  = (const float*)d_in[10];
    const float* W3  = (const float*)d_in[11];
    const float* b3  = (const float*)d_in[12];
    const float* g3  = (const float*)d_in[13];
    const float* be3 = (const float*)d_in[14];
    const float* m3  = (const float*)d_in[15];
    const float* v3  = (const float*)d_in[16];
    const float* W2  = (const float*)d_in[17];
    const float* b2  = (const float*)d_in[18];
    float* out = (float*)d_out;
    float* ws  = (float*)d_ws;

    prep_kernel<<<1, 256, 0, stream>>>(g1, be1, m1, v1, b1, g2, be2, m2, v2,
                                       W3, b3, g3, be3, m3, v3, b2, ws);
    stage1_kernel<<<NPIX / 64, 256, 0, stream>>>(x, W1, ws, ws + OFF_U);
    stage2_kernel<<<NOPIX / 8, 256, 0, stream>>>(x, W2, ws, ws + OFF_U, out);
}